// Round 7
// baseline (256.647 us; speedup 1.0000x reference)
//
#include <hip/hip_runtime.h>
#include <hip/hip_bf16.h>
#include <stdint.h>

// ---------- types ----------
typedef __attribute__((ext_vector_type(8))) short          bf16x8;
typedef __attribute__((ext_vector_type(4))) float          f32x4;
typedef __attribute__((ext_vector_type(4))) float          f4;
typedef __attribute__((ext_vector_type(8))) unsigned short u16x8;
typedef __attribute__((ext_vector_type(4))) unsigned short u16x4;

#define DEVINL __device__ __forceinline__

static constexpr int B  = 4;
static constexpr int S  = 4096;
static constexpr int D  = 256;
static constexpr int SP = 410;   // ceil(4096/10), SAME pooling, pad_lo = 2
static constexpr int KZ = 16;    // pv split-K factor
static constexpr int MO = B * SP;                 // 1640
static constexpr size_t PSLICE = (size_t)MO * D;  // 419840

DEVINL unsigned short f2bf(float x) {
  union { float f; unsigned u; } v; v.f = x;
  unsigned r = v.u + 0x7FFFu + ((v.u >> 16) & 1u);   // round-to-nearest-even
  return (unsigned short)(r >> 16);
}

DEVINL f32x4 mfma16(bf16x8 a, bf16x8 b, f32x4 c) {
  return __builtin_amdgcn_mfma_f32_16x16x32_bf16(a, b, c, 0, 0, 0);
}

typedef const __attribute__((address_space(1))) void* gas_t;
typedef __attribute__((address_space(3))) void*       las_t;
DEVINL void gload16(const void* g, void* l) {
  __builtin_amdgcn_global_load_lds((gas_t)g, (las_t)l, 16, 0, 0);
}

// counted-vmcnt pipeline helpers
DEVINL void cfence() { asm volatile("" ::: "memory"); }
DEVINL void barrier_mem() { cfence(); __builtin_amdgcn_s_barrier(); cfence(); }
// raw barrier + LDS fence (does NOT drain vmcnt)
DEVINL void lds_barrier() {
  asm volatile("s_waitcnt lgkmcnt(0)" ::: "memory");
  __builtin_amdgcn_s_barrier();
  cfence();
}
#define WAIT_VM(N) asm volatile("s_waitcnt vmcnt(" #N ")" ::: "memory")

// ---------- K0: fused weight transpose (z==3) + streaming qkv f32->bf16 (z<3) ----------
__global__ __launch_bounds__(256) void cvtwt_kernel(
    const float* __restrict__ xq, const float* __restrict__ xk, const float* __restrict__ xv,
    const float* __restrict__ wq, const float* __restrict__ wk,
    const float* __restrict__ wv, const float* __restrict__ wo,
    unsigned short* __restrict__ oq, unsigned short* __restrict__ ok, unsigned short* __restrict__ ov,
    unsigned short* __restrict__ wt)
{
  int z = blockIdx.y;
  if (z == 3) {
    if (blockIdx.x >= 1024) return;
    int idx = blockIdx.x * 256 + threadIdx.x;   // 4 * 256 * 256
    int mat = idx >> 16;
    int r   = idx & 65535;
    int n   = r >> 8;
    int k   = r & 255;
    const float* w = (mat == 0) ? wq : (mat == 1) ? wk : (mat == 2) ? wv : wo;
    wt[idx] = f2bf(w[k * 256 + n]);             // wt[mat][n][k] = w[k][n]
    return;
  }
  const float* x    = (z == 0) ? xq : (z == 1) ? xk : xv;
  unsigned short* o = (z == 0) ? oq : (z == 1) ? ok : ov;
  size_t i = ((size_t)blockIdx.x * 256 + threadIdx.x) * 8;
  f4 a = *reinterpret_cast<const f4*>(x + i);
  f4 c = *reinterpret_cast<const f4*>(x + i + 4);
  u16x8 h;
  h[0] = f2bf(a[0]); h[1] = f2bf(a[1]); h[2] = f2bf(a[2]); h[3] = f2bf(a[3]);
  h[4] = f2bf(c[0]); h[5] = f2bf(c[1]); h[6] = f2bf(c[2]); h[7] = f2bf(c[3]);
  *reinterpret_cast<u16x8*>(o + i) = h;
}

// ---------- K1: QKV projection GEMM (bf16, dbuf + counted vmcnt) ----------
// z==2 writes vpT[b][d][s] directly (transposed epilogue)
__global__ __launch_bounds__(512) void proj_kernel(
    const unsigned short* __restrict__ xq, const unsigned short* __restrict__ xk,
    const unsigned short* __restrict__ xv, const unsigned short* __restrict__ wt,
    const float* __restrict__ bq, const float* __restrict__ bk, const float* __restrict__ bv,
    unsigned short* __restrict__ qp, unsigned short* __restrict__ kp, unsigned short* __restrict__ vpT)
{
  int z = blockIdx.z;
  const unsigned short* X = (z == 0) ? xq : (z == 1) ? xk : xv;
  const unsigned short* W = wt + z * 65536;
  const float* bias       = (z == 0) ? bq : (z == 1) ? bk : bv;

  int m0 = blockIdx.x * 256;
  int n0 = blockIdx.y * 128;

  __shared__ __align__(16) struct { char A[2][32768]; char Bm[2][16384]; } sm;

  const char* Xc = (const char*)X;
  const char* Wc = (const char*)W;

  int tid  = threadIdx.x;
  int lane = tid & 63, wid = tid >> 6;
  int wr = wid >> 1, wc = wid & 1;       // 4x2 waves, 64x64 each
  int lrow = lane & 15, kseg = lane >> 4;

  f32x4 zero4 = {0.f, 0.f, 0.f, 0.f};
  f32x4 acc[4][4];
#pragma unroll
  for (int i = 0; i < 4; i++)
#pragma unroll
    for (int j = 0; j < 4; j++) acc[i][j] = zero4;

  auto stage = [&](int t, int buf) {
#pragma unroll
    for (int i = 0; i < 4; ++i) {                   // A: 256 rows x 64k
      int inst = wid * 4 + i;
      int sg   = inst * 64 + lane;
      int row  = sg >> 3, c16 = sg & 7;
      gload16(Xc + ((size_t)(m0 + row) << 9) + (t << 7) + ((c16 ^ (row & 7)) << 4),
              sm.A[buf] + inst * 1024);
    }
#pragma unroll
    for (int i = 0; i < 2; ++i) {                   // B: 128 rows x 64k
      int inst = wid * 2 + i;
      int sg   = inst * 64 + lane;
      int row  = sg >> 3, c16 = sg & 7;
      gload16(Wc + ((size_t)(n0 + row) << 9) + (t << 7) + ((c16 ^ (row & 7)) << 4),
              sm.Bm[buf] + inst * 1024);
    }
  };

  stage(0, 0);
#pragma unroll
  for (int t = 0; t < 4; ++t) {
    int cur = t & 1;
    if (t < 3) { stage(t + 1, cur ^ 1); WAIT_VM(6); } else { WAIT_VM(0); }
    barrier_mem();
    const char* Asm = sm.A[cur];
    const char* Bsm = sm.Bm[cur];
#pragma unroll
    for (int kk = 0; kk < 2; ++kk) {
      bf16x8 af[4], bfr[4];
#pragma unroll
      for (int mi = 0; mi < 4; ++mi) {
        int R = wr * 64 + mi * 16 + lrow;
        int c16 = (kk * 4 + kseg) ^ (R & 7);
        af[mi] = *reinterpret_cast<const bf16x8*>(Asm + R * 128 + c16 * 16);
      }
#pragma unroll
      for (int cf = 0; cf < 4; ++cf) {
        int nl = wc * 64 + cf * 16 + lrow;
        int c16 = (kk * 4 + kseg) ^ (nl & 7);
        bfr[cf] = *reinterpret_cast<const bf16x8*>(Bsm + nl * 128 + c16 * 16);
      }
#pragma unroll
      for (int mi = 0; mi < 4; ++mi)
#pragma unroll
        for (int cf = 0; cf < 4; ++cf)
          acc[mi][cf] = mfma16(af[mi], bfr[cf], acc[mi][cf]);
    }
    barrier_mem();
  }

  int r4 = kseg * 4;
  if (z < 2) {
    unsigned short* Out = (z == 0) ? qp : kp;
#pragma unroll
    for (int mi = 0; mi < 4; mi++)
#pragma unroll
      for (int cf = 0; cf < 4; cf++) {
        int n = n0 + wc * 64 + cf * 16 + lrow;
        float bv_ = bias[n];
#pragma unroll
        for (int r = 0; r < 4; r++) {
          int m = m0 + wr * 64 + mi * 16 + r4 + r;
          Out[(size_t)m * 256 + n] = f2bf(acc[mi][cf][r] + bv_);
        }
      }
  } else {
#pragma unroll
    for (int mi = 0; mi < 4; mi++)
#pragma unroll
      for (int cf = 0; cf < 4; cf++) {
        int n = n0 + wc * 64 + cf * 16 + lrow;
        float bv_ = bias[n];
        u16x4 hh;
#pragma unroll
        for (int r = 0; r < 4; r++) hh[r] = f2bf(acc[mi][cf][r] + bv_);
        int m  = m0 + wr * 64 + mi * 16 + r4;
        int bb = m >> 12, s = m & 4095;
        *reinterpret_cast<u16x4*>(&vpT[(size_t)bb * (256 * 4096) + (size_t)n * 4096 + s]) = hh;
      }
  }
}

// ---------- K2: persistent scores GEMM + fused max-pool (v4, barrier-free K-loop) ----------
// B (kp 128 rows x 256k = 64KB) LDS-resident, staged once. A (qp) goes global->regs
// (4 clamped base ptrs/tile + imm offsets), ping-pong prefetched one K-step ahead.
// No barriers in the K-loop; 2 lds_barrier pairs per tile for pooling only.
__global__ __launch_bounds__(512) void scores_pool_kernel(
    const unsigned short* __restrict__ qp, const unsigned short* __restrict__ kp,
    float* __restrict__ pooled)
{
  int id   = blockIdx.x;
  int nb   = id & 31;
  int b    = (id >> 5) & 3;
  int half = id >> 7;
  int wb0  = half ? 9 : 0;
  int nwb  = half ? 8 : 9;
  int n0   = nb * 128;

  __shared__ __align__(16) struct { char Bm[65536]; float pm[128 * 68]; } sm;
  char* Bsm = sm.Bm;
  float* pm = sm.pm;

  const char* qpc = (const char*)(qp + (size_t)b * S * 256);
  const char* kpc = (const char*)(kp + (size_t)b * S * 256);

  int tid  = threadIdx.x;
  int lane = tid & 63, wid = tid >> 6;
  int wr = wid >> 1, wc = wid & 1;       // 4x2 wave grid, each 64x64
  int lrow = lane & 15, kseg = lane >> 4;
  int h = kseg;

  // stage resident B: 128 rows x 256 k = 64KB, 8 insts/wave, pre-swizzled source
#pragma unroll
  for (int i = 0; i < 8; ++i) {
    int inst = wid * 8 + i;
    int sg   = inst * 64 + lane;
    int row  = sg >> 5, c16 = sg & 31;
    gload16(kpc + ((size_t)(n0 + row) << 9) + (((size_t)(c16 ^ (row & 7))) << 4),
            Bsm + inst * 1024);
  }
  WAIT_VM(0);
  barrier_mem();

  const char* abase[4];
  auto setbase = [&](int qb) {
#pragma unroll
    for (int mi = 0; mi < 4; ++mi) {
      int q = qb + wr * 64 + mi * 16 + lrow;
      q = (q < 0) ? 0 : ((q > S - 1) ? (S - 1) : q);
      abase[mi] = qpc + ((size_t)q << 9) + kseg * 16;
    }
  };
  auto loada = [&](bf16x8* dst, int ksoff) {
#pragma unroll
    for (int mi = 0; mi < 4; ++mi)
#pragma unroll
      for (int kk = 0; kk < 2; ++kk)
        dst[mi * 2 + kk] = *reinterpret_cast<const bf16x8*>(abase[mi] + ksoff + kk * 64);
  };

  f32x4 acc[4][4];
  auto mma_step = [&](int ks, const bf16x8* ause) {
    __builtin_amdgcn_s_setprio(1);
#pragma unroll
    for (int kk = 0; kk < 2; ++kk) {
      bf16x8 bfr[4];
#pragma unroll
      for (int cf = 0; cf < 4; ++cf) {
        int nl = wc * 64 + cf * 16 + lrow;
        int c16 = ((ks << 3) + (kk << 2) + kseg) ^ (nl & 7);
        bfr[cf] = *reinterpret_cast<const bf16x8*>(Bsm + nl * 512 + c16 * 16);
      }
#pragma unroll
      for (int mi = 0; mi < 4; ++mi)
#pragma unroll
        for (int cf = 0; cf < 4; ++cf)
          acc[mi][cf] = mfma16(ause[mi * 2 + kk], bfr[cf], acc[mi][cf]);
    }
    __builtin_amdgcn_s_setprio(0);
  };

  bf16x8 aA[8], aB[8];
  setbase(wb0 * 250 - 2);
  loada(aA, 0);

  for (int i = 0; i < nwb; ++i) {
    int wb = wb0 + i, w0 = wb * 25;
    int qb = w0 * 10 - 2;
    int nwin = SP - w0; if (nwin > 25) nwin = 25;

    f32x4 zero4 = {0.f, 0.f, 0.f, 0.f};
#pragma unroll
    for (int mi = 0; mi < 4; mi++)
#pragma unroll
      for (int cf = 0; cf < 4; cf++) acc[mi][cf] = zero4;

    // 4 K-steps, A ping-pong prefetch, zero barriers
    loada(aB, 128);  mma_step(0, aA);
    loada(aA, 256);  mma_step(1, aB);
    loada(aB, 384);  mma_step(2, aA);
    if (i + 1 < nwb) { setbase(qb + 250); /* next tile qb = (w0+25)*10-2 = qb+250 */ loada(aA, 0); }
    mma_step(3, aB);

    // ---- pooling: pair-max -> pm [128 pairs][stride 68] -> 5-way window max
#pragma unroll
    for (int c = 0; c < 2; ++c) {
      if (wc == c) {
#pragma unroll
        for (int mi = 0; mi < 4; ++mi) {
          int p = wr * 32 + mi * 8 + h * 2;
#pragma unroll
          for (int cf = 0; cf < 4; ++cf) {
            int col = cf * 16 + lrow;
            pm[p * 68 + col]       = fmaxf(acc[mi][cf][0], acc[mi][cf][1]);
            pm[(p + 1) * 68 + col] = fmaxf(acc[mi][cf][2], acc[mi][cf][3]);
          }
        }
      }
      lds_barrier();
      for (int s = tid; s < 1600; s += 512) {
        int j = s >> 6, col = s & 63;
        if (j < nwin) {
          float m = -3.4e38f;
#pragma unroll
          for (int t5 = 0; t5 < 5; ++t5) {
            int p  = 5 * j + t5;
            int q0 = qb + 2 * p;
            if (q0 >= 0 && q0 < S) m = fmaxf(m, pm[p * 68 + col]);
          }
          pooled[((size_t)b * SP + w0 + j) * 4096 + n0 + c * 64 + col] = m * 0.0625f;
        }
      }
      lds_barrier();
    }
  }
}

// ---------- K3: row softmax (4096 cols), fp32 in, bf16 out ----------
__global__ __launch_bounds__(256) void softmax_kernel(
    const float* __restrict__ pooled, unsigned short* __restrict__ attn)
{
  int row = blockIdx.x;
  const float* p = pooled + (size_t)row * 4096;
  unsigned short* a = attn + (size_t)row * 4096;
  int tid = threadIdx.x;
  int lane = tid & 63, wid = tid >> 6;

  f4 v[4];
  float mx = -3.4e38f;
#pragma unroll
  for (int i = 0; i < 4; i++) {
    v[i] = *reinterpret_cast<const f4*>(&p[i * 1024 + tid * 4]);
    mx = fmaxf(mx, fmaxf(fmaxf(v[i][0], v[i][1]), fmaxf(v[i][2], v[i][3])));
  }
#pragma unroll
  for (int off = 32; off > 0; off >>= 1) mx = fmaxf(mx, __shfl_xor(mx, off, 64));
  __shared__ float redm[4];
  __shared__ float reds[4];
  if (lane == 0) redm[wid] = mx;
  __syncthreads();
  mx = fmaxf(fmaxf(redm[0], redm[1]), fmaxf(redm[2], redm[3]));

  float e[16];
  float sum = 0.f;
#pragma unroll
  for (int i = 0; i < 4; i++)
#pragma unroll
    for (int j = 0; j < 4; j++) {
      float t = __expf(v[i][j] - mx);
      e[i * 4 + j] = t;
      sum += t;
    }
#pragma unroll
  for (int off = 32; off > 0; off >>= 1) sum += __shfl_xor(sum, off, 64);
  if (lane == 0) reds[wid] = sum;
  __syncthreads();
  sum = reds[0] + reds[1] + reds[2] + reds[3];
  float inv = 1.f / sum;
#pragma unroll
  for (int i = 0; i < 4; i++) {
    u16x4 o;
#pragma unroll
    for (int j = 0; j < 4; j++) o[j] = f2bf(e[i * 4 + j] * inv);
    *reinterpret_cast<u16x4*>(&a[i * 1024 + tid * 4]) = o;
  }
}

// ---------- K4: PV GEMM, split-K=16, dbuf + counted vmcnt, partials to ws ----------
__global__ __launch_bounds__(256) void pv_kernel(
    const unsigned short* __restrict__ attn, const unsigned short* __restrict__ vpT,
    float* __restrict__ part)
{
  int bx = blockIdx.x;
  int b  = bx >> 2, mt = bx & 3;
  int m0 = mt * 128;
  int n0 = blockIdx.y * 128;
  int kz = blockIdx.z;
  int k0b = kz * 512;

  const char* Ac = (const char*)(attn + (size_t)b * SP * 4096);
  const char* Bc = (const char*)(vpT  + (size_t)b * 256 * 4096);
  float* Pz = part + (size_t)kz * PSLICE;

  __shared__ __align__(16) struct { char A[2][16384]; char Bm[2][16384]; } sm;

  int tid  = threadIdx.x;
  int lane = tid & 63, wid = tid >> 6;
  int wr = wid >> 1, wc = wid & 1;
  int lrow = lane & 15, kseg = lane >> 4;

  f32x4 zero4 = {0.f, 0.f, 0.f, 0.f};
  f32x4 acc[4][4];
#pragma unroll
  for (int i = 0; i < 4; i++)
#pragma unroll
    for (int j = 0; j < 4; j++) acc[i][j] = zero4;

  auto stage = [&](int t, int buf) {
#pragma unroll
    for (int i = 0; i < 4; ++i) {
      int inst = wid * 4 + i;
      int sg   = inst * 64 + lane;
      int row  = sg >> 3, c16 = sg & 7;
      int m = m0 + row; m = (m > SP - 1) ? (SP - 1) : m;
      gload16(Ac + (size_t)m * 8192 + k0b + (t << 7) + ((c16 ^ (row & 7)) << 4),
              sm.A[buf] + inst * 1024);
    }
#pragma unroll
    for (int i = 0; i < 4; ++i) {
      int inst = wid * 4 + i;
      int sg   = inst * 64 + lane;
      int row  = sg >> 3, c16 = sg & 7;
      gload16(Bc + (size_t)(n0 + row) * 8192 + k0b + (t << 7) + ((c16 ^ (row & 7)) << 4),
              sm.Bm[buf] + inst * 1024);
    }
  };

  stage(0, 0);
#pragma unroll
  for (int t = 0; t < 4; ++t) {
    int cur = t & 1;
    if (t < 3) { stage(t + 1, cur ^ 1); WAIT_VM(8); } else { WAIT_VM(0); }
    barrier_mem();
    const char* Asm = sm.A[cur];
    const char* Bsm = sm.Bm[cur];
#pragma unroll
    for (int kk = 0; kk < 2; ++kk) {
      bf16x8 af[4], bfr[4];
#pragma unroll
      for (int mi = 0; mi < 4; ++mi) {
        int R = wr * 64 + mi * 16 + lrow;
        int c16 = (kk * 4 + kseg) ^ (R & 7);
        af[mi] = *reinterpret_cast<const bf16x8*>(Asm + R * 128 + c16 * 16);
      }
#pragma unroll
      for (int cf = 0; cf < 4; ++cf) {
        int nl = wc * 64 + cf * 16 + lrow;
        int c16 = (kk * 4 + kseg) ^ (nl & 7);
        bfr[cf] = *reinterpret_cast<const bf16x8*>(Bsm + nl * 128 + c16 * 16);
      }
#pragma unroll
      for (int mi = 0; mi < 4; ++mi)
#pragma unroll
        for (int cf = 0; cf < 4; ++cf)
          acc[mi][cf] = mfma16(af[mi], bfr[cf], acc[mi][cf]);
    }
    barrier_mem();
  }

  int r4 = kseg * 4;
#pragma unroll
  for (int mi = 0; mi < 4; mi++)
#pragma unroll
    for (int cf = 0; cf < 4; cf++) {
      int n = n0 + wc * 64 + cf * 16 + lrow;
#pragma unroll
      for (int r = 0; r < 4; r++) {
        int m = m0 + wr * 64 + mi * 16 + r4 + r;
        if (m < SP) Pz[((size_t)b * SP + m) * 256 + n] = acc[mi][cf][r];
      }
    }
}

// ---------- K4b: sum 16 partials -> ctx bf16 ----------
__global__ __launch_bounds__(256) void reduce_kernel(
    const float* __restrict__ part, unsigned short* __restrict__ ctxb)
{
  size_t i = (size_t)blockIdx.x * 256 + threadIdx.x;
  float s = 0.f;
#pragma unroll
  for (int z = 0; z < KZ; ++z) s += part[z * PSLICE + i];
  ctxb[i] = f2bf(s);
}

// ---------- K5: out = ctx @ wo + bo (fp32 out), dbuf + counted vmcnt ----------
__global__ __launch_bounds__(512) void out_kernel(
    const unsigned short* __restrict__ ctxb, const unsigned short* __restrict__ woT,
    const float* __restrict__ bo, float* __restrict__ out)
{
  int m0 = blockIdx.x * 256;
  int n0 = blockIdx.y * 128;

  __shared__ __align__(16) struct { char A[2][32768]; char Bm[2][16384]; } sm;

  const char* Xc = (const char*)ctxb;
  const char* Wc = (const char*)woT;

  int tid  = threadIdx.x;
  int lane = tid & 63, wid = tid >> 6;
  int wr = wid >> 1, wc = wid & 1;
  int lrow = lane & 15, kseg = lane >> 4;

  f32x4 zero4 = {0.f, 0.f, 0.f, 0.f};
  f32x4 acc[4][4];
#pragma unroll
  for (int i = 0; i < 4; i++)
#pragma unroll
    for (int j = 0; j < 4; j++) acc[i][j] = zero4;

  auto stage = [&](int t, int buf) {
#pragma unroll
    for (int i = 0; i < 4; ++i) {
      int inst = wid * 4 + i;
      int sg   = inst * 64 + lane;
      int row  = sg >> 3, c16 = sg & 7;
      int m = m0 + row; m = (m > MO - 1) ? (MO - 1) : m;
      gload16(Xc + ((size_t)m << 9) + (t << 7) + ((c16 ^ (row & 7)) << 4),
              sm.A[buf] + inst * 1024);
    }
#pragma unroll
    for (int i = 0; i < 2; ++i) {
      int inst = wid * 2 + i;
      int sg   = inst * 64 + lane;
      int row  = sg >> 3, c16 = sg & 7;
      gload16(Wc + ((size_t)(n0 + row) << 9) + (t << 7) + ((c16 ^ (row & 7)) << 4),
              sm.Bm[buf] + inst * 1024);
    }
  };

  stage(0, 0);
#pragma unroll
  for (int t = 0; t < 4; ++t) {
    int cur = t & 1;
    if (t < 3) { stage(t + 1, cur ^ 1); WAIT_VM(6); } else { WAIT_VM(0); }
    barrier_mem();
    const char* Asm = sm.A[cur];
    const char* Bsm = sm.Bm[cur];
#pragma unroll
    for (int kk = 0; kk < 2; ++kk) {
      bf16x8 af[4], bfr[4];
#pragma unroll
      for (int mi = 0; mi < 4; ++mi) {
        int R = wr * 64 + mi * 16 + lrow;
        int c16 = (kk * 4 + kseg) ^ (R & 7);
        af[mi] = *reinterpret_cast<const bf16x8*>(Asm + R * 128 + c16 * 16);
      }
#pragma unroll
      for (int cf = 0; cf < 4; ++cf) {
        int nl = wc * 64 + cf * 16 + lrow;
        int c16 = (kk * 4 + kseg) ^ (nl & 7);
        bfr[cf] = *reinterpret_cast<const bf16x8*>(Bsm + nl * 128 + c16 * 16);
      }
#pragma unroll
      for (int mi = 0; mi < 4; ++mi)
#pragma unroll
        for (int cf = 0; cf < 4; ++cf)
          acc[mi][cf] = mfma16(af[mi], bfr[cf], acc[mi][cf]);
    }
    barrier_mem();
  }

  int r4 = kseg * 4;
#pragma unroll
  for (int mi = 0; mi < 4; mi++)
#pragma unroll
    for (int cf = 0; cf < 4; cf++) {
      int n = n0 + wc * 64 + cf * 16 + lrow;
      float bv_ = bo[n];
#pragma unroll
      for (int r = 0; r < 4; r++) {
        int m = m0 + wr * 64 + mi * 16 + r4 + r;
        if (m < MO) out[(size_t)m * 256 + n] = acc[mi][cf][r] + bv_;
      }
    }
}

// ---------- launch ----------
extern "C" void kernel_launch(void* const* d_in, const int* in_sizes, int n_in,
                              void* d_out, int out_size, void* d_ws, size_t ws_size,
                              hipStream_t stream)
{
  const float* v  = (const float*)d_in[0];
  const float* k  = (const float*)d_in[1];
  const float* q  = (const float*)d_in[2];
  const float* wq = (const float*)d_in[3];
  const float* bq = (const float*)d_in[4];
  const float* wk = (const float*)d_in[5];
  const float* bk = (const float*)d_in[6];
  const float* wv = (const float*)d_in[7];
  const float* bv = (const float*)d_in[8];
  const float* wo = (const float*)d_in[9];
  const float* bo = (const float*)d_in[10];
  float* out = (float*)d_out;

  char* ws = (char*)d_ws;
  size_t off = 0;
  auto alloc = [&](size_t bytes) -> void* {
    void* p = ws + off;
    off += (bytes + 255) & ~(size_t)255;
    return p;
  };
  unsigned short* qp   = (unsigned short*)alloc((size_t)B * S * D * 2);     // 8 MB
  unsigned short* kp   = (unsigned short*)alloc((size_t)B * S * D * 2);     // 8 MB
  unsigned short* vpT  = (unsigned short*)alloc((size_t)B * S * D * 2);     // 8 MB
  unsigned short* wt   = (unsigned short*)alloc((size_t)4 * 256 * 256 * 2); // 0.5 MB
  unsigned short* ctxb = (unsigned short*)alloc(PSLICE * 2);                // 0.84 MB
  char* shared_region  = (char*)alloc((size_t)B * SP * 4096 * 4);
  unsigned short* attn = (unsigned short*)alloc((size_t)B * SP * 4096 * 2); // 13.4 MB

  unsigned short* qx = (unsigned short*)shared_region;
  unsigned short* kx = qx + (size_t)B * S * D;
  unsigned short* vx = kx + (size_t)B * S * D;
  float* pooled = (float*)shared_region;
  float* part   = (float*)shared_region;

  cvtwt_kernel<<<dim3(2048, 4), 256, 0, stream>>>(q, k, v, wq, wk, wv, wo, qx, kx, vx, wt);
  proj_kernel<<<dim3(64, 2, 3), 512, 0, stream>>>(qx, kx, vx, wt, bq, bk, bv, qp, kp, vpT);
  scores_pool_kernel<<<256, 512, 0, stream>>>(qp, kp, pooled);
  softmax_kernel<<<B * SP, 256, 0, stream>>>(pooled, attn);
  pv_kernel<<<dim3(16, 2, KZ), 256, 0, stream>>>(attn, vpT, part);
  reduce_kernel<<<(int)(PSLICE / 256), 256, 0, stream>>>(part, ctxb);
  out_kernel<<<dim3(7, 2), 512, 0, stream>>>(ctxb, wt + 3 * 65536, bo, out);
}